// Round 5
// baseline (448.620 us; speedup 1.0000x reference)
//
#include <hip/hip_runtime.h>

#define LQ 384
#define DF 64
#define NWIN 16
#define PERW 15      // NG + NF
#define STEPW 16     // 1 + NG + NF
#define NPAIR 240    // NWIN * PERW
#define NWAVE 6
#define PW 32        // panel width (cols per round)
#define NPANEL 12    // 384 / PW
#define NROUND 17    // NPANEL + NWAVE - 1
#define DCS 68       // D-tile column stride (col-major [32 cols][68])
#define C2  0.28853900817779268f   // 1/(5*ln2)  (pre-scale: R' = R*C2)
#define L2C 3.4657359027997265f    // 5*ln2      (unscale at extraction)
#define BIGS (1e9f * C2)           // BIG in scaled domain

typedef float v2f __attribute__((ext_vector_type(2)));

__device__ __forceinline__ float fexp2(float x) { return __builtin_amdgcn_exp2f(x); }
__device__ __forceinline__ float flog2(float x) { return __builtin_amdgcn_logf(x); }

// wave_shr:1 -- lane l gets lane l-1's value (VALU pipe). lane0 keeps own (fixed up).
__device__ __forceinline__ float wshr1f(float x) {
  int xi = __float_as_int(x);
  return __int_as_float(__builtin_amdgcn_update_dpp(xi, xi, 0x138, 0xF, 0xF, false));
}

// ---------------------------------------------------------------------------
// Log-domain soft-DTW (validated round-3 dataflow), pre-scaled by C2 so the
// per-step chain is: DPP -> min3 -> 3x(sub+exp2) -> add -> log2 -> add.
// B is read straight from global in the GEMM (no Bsh) => LDS 57KB => 2 blk/CU.
// ---------------------------------------------------------------------------
__global__ __launch_bounds__(LQ, 3) void sdtw_kernel(const float* __restrict__ data,
                                                     const int* __restrict__ lens,
                                                     float* __restrict__ dist) {
  __shared__ __align__(16) float Dt[NWAVE][32 * DCS];    // 52224 B (D*C2 values)
  __shared__ __align__(16) float sqA[LQ];                // 1536 B
  __shared__ __align__(16) float sqB[LQ];                // 1536 B
  __shared__ __align__(16) float bnd[NWAVE][2][36];      // 1728 B   (~57 KB total)

  const int p_id = blockIdx.x;
  const int wwin = p_id / PERW;
  const int o = p_id - wwin * PERW;
  const int aRow = wwin * STEPW;
  const int bRow = aRow + 1 + o;
  const int la = lens[aRow];
  const int lb = lens[bRow];
  const int tid = threadIdx.x;
  const int w = tid >> 6;
  const int lane = tid & 63;

  const float* __restrict__ A  = data + (size_t)aRow * LQ * DF;
  const float* __restrict__ Bp = data + (size_t)bRow * LQ * DF;

  // ---- sqA / sqB from global (once) ----
  {
    const float4* A4 = (const float4*)(A + (size_t)tid * DF);
    float s = 0.f;
#pragma unroll
    for (int k = 0; k < 16; ++k) {
      float4 v = A4[k];
      s = fmaf(v.x, v.x, s); s = fmaf(v.y, v.y, s);
      s = fmaf(v.z, v.z, s); s = fmaf(v.w, v.w, s);
    }
    sqA[tid] = s;
  }
  {
    const float4* B4 = (const float4*)(Bp + (size_t)tid * DF);
    float s = 0.f;
#pragma unroll
    for (int k = 0; k < 16; ++k) {
      float4 v = B4[k];
      s = fmaf(v.x, v.x, s); s = fmaf(v.y, v.y, s);
      s = fmaf(v.z, v.z, s); s = fmaf(v.w, v.w, s);
    }
    sqB[tid] = s;
  }
  __syncthreads();

  // extraction target: R[la][lb] at wave wt, lane it, panel pt, step tstar
  const int wt = (la - 1) >> 6;
  const int it = (la - 1) & 63;
  const int pt = (lb - 1) >> 5;
  const int tstar = it + ((lb - 1) & 31);
  const int rstar = wt + pt;
  const float scale = L2C / (float)(la + lb);   // unscale * 1/(la+lb)

  float leftR = BIGS;               // R'[row][panel_start-1]; col 0 => BIG
  float* DtW = &Dt[w][0];
  const int rg = lane >> 3, cg = lane & 7;   // GEMM: 8 rows x 4 cols per lane
  const bool waveActive = (64 * w < la);
  const int wn = (w + 1 < NWAVE) ? (w + 1) : 0;

  // this lane's 8 A-row norms (fixed across rounds)
  float sa8[8];
  *(float4*)&sa8[0] = *(const float4*)&sqA[64 * w + 8 * rg];
  *(float4*)&sa8[4] = *(const float4*)&sqA[64 * w + 8 * rg + 4];

  for (int r = 0; r < NROUND; ++r) {
    __syncthreads();                // protects bnd double-buffer across waves
    const int p = r - w;
    if ((unsigned)p < (unsigned)NPANEL && waveActive && (32 * p < lb)) {
      // ===== GEMM: rows 64w..64w+63 x cols 32p..32p+31; A,B from global =====
      v2f acc[8][4];
#pragma unroll
      for (int a_ = 0; a_ < 8; ++a_)
#pragma unroll
        for (int b_ = 0; b_ < 4; ++b_) { acc[a_][b_].x = 0.f; acc[a_][b_].y = 0.f; }
      const float4* A4  = (const float4*)(A  + (size_t)(64 * w + 8 * rg) * DF);
      const float4* B4g = (const float4*)(Bp + (size_t)(PW * p + 4 * cg) * DF);
#pragma unroll
      for (int kk = 0; kk < 16; ++kk) {
        v2f a0[8], a1[8];
#pragma unroll
        for (int rr = 0; rr < 8; ++rr) {
          float4 v = A4[rr * 16 + kk];
          a0[rr].x = v.x; a0[rr].y = v.y; a1[rr].x = v.z; a1[rr].y = v.w;
        }
        v2f b0[4], b1[4];
#pragma unroll
        for (int cc = 0; cc < 4; ++cc) {
          float4 v = B4g[cc * 16 + kk];
          b0[cc].x = v.x; b0[cc].y = v.y; b1[cc].x = v.z; b1[cc].y = v.w;
        }
#pragma unroll
        for (int rr = 0; rr < 8; ++rr)
#pragma unroll
          for (int cc = 0; cc < 4; ++cc) {
            acc[rr][cc] = __builtin_elementwise_fma(a0[rr], b0[cc], acc[rr][cc]);
            acc[rr][cc] = __builtin_elementwise_fma(a1[rr], b1[cc], acc[rr][cc]);
          }
      }
      // ===== epilogue: D' = (sqA + sqB - 2*dot) * C2, store col-major =======
      {
        float4 sb = *(const float4*)&sqB[PW * p + 4 * cg];
        float sbv[4] = {sb.x, sb.y, sb.z, sb.w};
#pragma unroll
        for (int cc = 0; cc < 4; ++cc) {
          float4 lo, hi;
          lo.x = (sa8[0] + sbv[cc] - 2.f * (acc[0][cc].x + acc[0][cc].y)) * C2;
          lo.y = (sa8[1] + sbv[cc] - 2.f * (acc[1][cc].x + acc[1][cc].y)) * C2;
          lo.z = (sa8[2] + sbv[cc] - 2.f * (acc[2][cc].x + acc[2][cc].y)) * C2;
          lo.w = (sa8[3] + sbv[cc] - 2.f * (acc[3][cc].x + acc[3][cc].y)) * C2;
          hi.x = (sa8[4] + sbv[cc] - 2.f * (acc[4][cc].x + acc[4][cc].y)) * C2;
          hi.y = (sa8[5] + sbv[cc] - 2.f * (acc[5][cc].x + acc[5][cc].y)) * C2;
          hi.z = (sa8[6] + sbv[cc] - 2.f * (acc[6][cc].x + acc[6][cc].y)) * C2;
          hi.w = (sa8[7] + sbv[cc] - 2.f * (acc[7][cc].x + acc[7][cc].y)) * C2;
          float* dp = &DtW[(4 * cg + cc) * DCS + 8 * rg];
          *(float4*)dp = lo;
          *(float4*)(dp + 4) = hi;
        }
      }
      __builtin_amdgcn_sched_barrier(0);   // D stores before D reads

      // ===== DP: 96 anti-diagonal steps, DPP shift, no barriers =============
      float* bndR = &bnd[w][r & 1][0];
      float* bndW = &bnd[wn][(r + 1) & 1][0];
      const bool wr63 = (lane == 63) && (w + 1 < NWAVE) && (64 * (w + 1) < la);
      if (wr63) bndW[0] = leftR;          // R'[64(w+1)][32p]

      // 3-deep register prefetch of D'; (&31) wrap keeps banks distinct
      float d0, d1, d2;
      {
        int j0 = (0 - lane) & 31, j1 = (1 - lane) & 31, j2 = (2 - lane) & 31;
        d0 = DtW[j0 * DCS + lane];
        d1 = DtW[j1 * DCS + lane];
        d2 = DtW[j2 * DCS + lane];
      }
      float cur = leftR;     // R'[row][j-1]
      float extv = 0.f;
      float bq0[4] = {BIGS, BIGS, BIGS, BIGS}, bq1[4] = {BIGS, BIGS, BIGS, BIGS};
      if (w > 0) {
        float4 q0 = *(const float4*)&bndR[0];
        float4 q1 = *(const float4*)&bndR[4];
        bq0[0]=q0.x; bq0[1]=q0.y; bq0[2]=q0.z; bq0[3]=q0.w;
        bq1[0]=q1.x; bq1[1]=q1.y; bq1[2]=q1.z; bq1[3]=q1.w;
      }
      float s2;              // rolling diag = previous step's s1
      {
        float fix0 = (w == 0) ? ((p == 0) ? 0.f : BIGS) : bq0[0];
        s2 = (lane == 0) ? fix0 : cur;
      }
      const bool extRound = (w == wt) && (r == rstar);

#define STEP(T, BUPRAW) do {                                                \
        float s1 = wshr1f(cur);                                             \
        if (lane == 0) s1 = (w == 0) ? BIGS : (BUPRAW);                     \
        int jl = (T) - lane;                                                \
        float dv = d0; d0 = d1; d1 = d2;                                    \
        { int jc = ((T) + 3 - lane) & 31;                                   \
          d2 = DtW[jc * DCS + lane]; }                                      \
        float m = fminf(s2, fminf(s1, cur));                                \
        float e = fexp2(m - s2) + fexp2(m - s1) + fexp2(m - cur);           \
        float val = dv + m - flog2(e);                                      \
        s2 = s1;                                                            \
        if (extRound && tstar == (T) && lane == it) extv = val;             \
        if ((unsigned)jl < 32u) {                                           \
          cur = val;                                                        \
          if (wr63) bndW[jl + 1] = val;                                     \
        }                                                                   \
      } while (0)

      for (int tq = 0; tq < 24; ++tq) {
        const int tb = tq * 4;
        float bq2[4];
        {
          int off = tb + 8; off = off > 32 ? 32 : off;
          float4 q = *(const float4*)&bndR[off];
          bq2[0]=q.x; bq2[1]=q.y; bq2[2]=q.z; bq2[3]=q.w;
        }
        STEP(tb + 0, bq0[1]);
        STEP(tb + 1, bq0[2]);
        STEP(tb + 2, bq0[3]);
        STEP(tb + 3, bq1[0]);
        bq0[0]=bq1[0]; bq0[1]=bq1[1]; bq0[2]=bq1[2]; bq0[3]=bq1[3];
        bq1[0]=bq2[0]; bq1[1]=bq2[1]; bq1[2]=bq2[2]; bq1[3]=bq2[3];
      }
#undef STEP
      if (extRound && lane == it) dist[p_id] = extv * scale;
      leftR = cur;            // R'[row][32p+32] -> next panel's left boundary
    }
  }
}

// ---------------------------------------------------------------------------
// Loss reduction over 16 windows (validated rounds 1-3).
// ---------------------------------------------------------------------------
__device__ __forceinline__ float median5(const float* v) {
#pragma unroll
  for (int i = 0; i < 5; ++i) {
    int c = 0;
#pragma unroll
    for (int j = 0; j < 5; ++j)
      c += (v[j] < v[i]) || ((v[j] == v[i]) && (j < i));
    if (c == 2) return v[i];
  }
  return v[0];
}

__global__ void loss_kernel(const float* __restrict__ dist, float* __restrict__ out) {
  __shared__ float acc[NWIN];
  const int w = threadIdx.x;
  if (w < NWIN) {
    float dg[5], dn[10];
#pragma unroll
    for (int g = 0; g < 5; ++g)  dg[g] = dist[w * PERW + g];
#pragma unroll
    for (int n = 0; n < 10; ++n) dn[n] = dist[w * PERW + 5 + n];

    float lk = 0.f; int nz = 0;
#pragma unroll
    for (int g = 0; g < 5; ++g)
#pragma unroll
      for (int n = 0; n < 10; ++n) {
        float t = dg[g] + 1.0f - dn[n];
        if (t > 0.f) { lk += t; ++nz; }
      }
    float lv = lk / (1.0f + (float)nz);

    float sp = 0.f;
#pragma unroll
    for (int g = 0; g < 5; ++g) sp += dg[g];
    float only_pos = sp * (0.01f / 5.0f);

    float mg = median5(dg);
    float ms = median5(dn);

    int err = 0;
#pragma unroll
    for (int g = 0; g < 5; ++g) {
      err += ((dg[g] < mg) && (dn[g] < mg));
      err += ((dg[g] > ms) && (dn[g] > ms));
      err += ((dg[g] < mg) && (dn[5 + g] < mg));
      err += ((dg[g] > ms) && (dn[5 + g] > ms));
    }
    float offset = (float)err * (1.0f / 50.0f);

    acc[w] = lv + only_pos + offset;
  }
  __syncthreads();
  if (w == 0) {
    float s = 0.f;
#pragma unroll
    for (int i = 0; i < NWIN; ++i) s += acc[i];
    out[0] = s / (float)NWIN;
  }
}

// ---------------------------------------------------------------------------
extern "C" void kernel_launch(void* const* d_in, const int* in_sizes, int n_in,
                              void* d_out, int out_size, void* d_ws, size_t ws_size,
                              hipStream_t stream) {
  const float* data = (const float*)d_in[0];
  const int* lens   = (const int*)d_in[1];
  float* dist = (float*)d_ws;

  sdtw_kernel<<<NPAIR, LQ, 0, stream>>>(data, lens, dist);
  loss_kernel<<<1, 64, 0, stream>>>(dist, (float*)d_out);
}